// Round 7
// baseline (39103.766 us; speedup 1.0000x reference)
//
#include <hip/hip_runtime.h>
#include <hip/hip_cooperative_groups.h>
#include <math.h>

namespace cg = cooperative_groups;

#define B_    32
#define TE    1024
#define TD    512
#define E_    512
#define F_    32
#define K_    31
#define KH    15
#define CHUNK 128
#define NCH   (TE / CHUNK)        // 8 chunks per batch row
#define NBLK  (B_ * NCH)          // 256 blocks = 1 per CU (co-resident)

typedef __attribute__((ext_vector_type(8))) short short8;
typedef __attribute__((ext_vector_type(4))) float f32x4;

__device__ __forceinline__ unsigned short f2bf(float x) {   // RNE f32->bf16
    unsigned u = __float_as_uint(x);
    unsigned r = (u + 0x7fffu + ((u >> 16) & 1u)) >> 16;
    return (unsigned short)r;
}
__device__ __forceinline__ float bf2f(unsigned short h) {
    return __uint_as_float(((unsigned)h) << 16);
}

// ---------------------------------------------------------------------------
// Prologue (once per call): w_loc (F,U) -> transposed bf16 hi/lo [u][c].
// ---------------------------------------------------------------------------
__global__ void prep_kernel(const float* __restrict__ wloc,
                            unsigned short* __restrict__ WTh,
                            unsigned short* __restrict__ WTl)
{
    const int u = threadIdx.x;                 // 512 threads
    #pragma unroll
    for (int c = 0; c < F_; ++c) {
        float x = wloc[c * 512 + u];
        unsigned short h = f2bf(x);
        WTh[u * F_ + c] = h;
        WTl[u * F_ + c] = f2bf(x - bf2f(h));
    }
}

// ---------------------------------------------------------------------------
// Persistent cooperative kernel: all TD steps, enc held in REGISTERS.
// Block (b, chunk) owns t in [chunk*128, +128) for the whole decode.
// Thread (wave w, quad q, n16) epilogue-owns t = tt*16+q*4+r (tt<8, r<4),
// u = 64w+16*ut+n16 (ut<4)  ->  encR[8][4][4] = exactly its 128 enc values.
// Per step: phase1 finish s-1 softmax (praw halo from global, written one
// grid.sync ago) -> paW (LDS, persistent); conv -> bf16 A-frags; split-bf16
// MFMA (96/wave); tanh epilogue vs encR; write praw_s + chunk partial;
// __threadfence + grid.sync. praw/Ps double-buffered => 1 sync/step.
// Cross-step global traffic ~350 KB/step, so the sync's L2 invalidation is
// harmless (R2's failure was 49 MB/step enc refetch; enc now in VGPRs).
// ---------------------------------------------------------------------------
__global__ __launch_bounds__(512, 2)
void persist_kernel(const float* __restrict__ enc,   // B,TE,E
                    const float* __restrict__ dec,   // B,TD,E
                    const float* __restrict__ cw,    // K,1,F
                    const float* __restrict__ cb,    // F
                    const unsigned short* __restrict__ WTh, // U,F bf16 hi
                    const unsigned short* __restrict__ WTl, // U,F bf16 lo
                    const float* __restrict__ va,    // U
                    const float* __restrict__ ba,    // U
                    float* __restrict__ pr0,         // B,TE praw buf 0
                    float* __restrict__ pr1,         // B,TE praw buf 1
                    float* __restrict__ Ps0,         // B,NCH partials buf 0
                    float* __restrict__ Ps1,         // B,NCH partials buf 1
                    float* __restrict__ eout)        // B,TD,TE
{
    __shared__ __align__(16) unsigned short fThS[CHUNK * F_]; // 8 KB
    __shared__ __align__(16) unsigned short fTlS[CHUNK * F_]; // 8 KB
    __shared__ float cwS[K_ * F_];
    __shared__ float cbS[F_];
    __shared__ float paW[CHUNK + 2 * KH + 2];                 // 160, persistent
    __shared__ float red[NCH];
    __shared__ float redT[CHUNK][9];

    const int tid   = threadIdx.x;
    const int g     = tid & 63;
    const int w     = tid >> 6;               // wave 0..7
    const int q     = g >> 4;                 // quad 0..3
    const int n16   = g & 15;
    const int b     = blockIdx.x >> 3;
    const int chunk = blockIdx.x & 7;
    const int t0    = chunk * CHUNK;
    const float L2E = 1.4426950408889634f;
    const float KK  = 2.885390081777927f;     // 2*log2(e)

    // ---- B-fragments + va/ba for this wave's u range [64w, 64w+64) ----
    short8 bh[4], bl[4];
    int   uu[4];
    float vvr[4], bar[4];
    #pragma unroll
    for (int ut = 0; ut < 4; ++ut) {
        uu[ut]  = w * 64 + ut * 16 + n16;
        bh[ut]  = ((const short8*)WTh)[uu[ut] * 4 + q];
        bl[ut]  = ((const short8*)WTl)[uu[ut] * 4 + q];
        vvr[ut] = va[uu[ut]];
        bar[ut] = ba[uu[ut]];
    }

    // ---- enc -> registers: this thread's 128 epilogue values ----
    float encR[8][4][4];
    #pragma unroll
    for (int tt = 0; tt < 8; ++tt)
        #pragma unroll
        for (int r = 0; r < 4; ++r) {
            const float* erow = enc + ((size_t)b * TE + t0 + tt * 16 + q * 4 + r) * E_;
            #pragma unroll
            for (int ut = 0; ut < 4; ++ut)
                encR[tt][r][ut] = erow[uu[ut]];
        }

    // ---- stage conv weights, zero paW ----
    for (int i = tid; i < K_ * F_; i += 512) cwS[i] = cw[i];
    if (tid < F_) cbS[tid] = cb[tid];
    if (tid < CHUNK + 2 * KH + 2) paW[tid] = 0.0f;
    __syncthreads();

    cg::grid_group grid = cg::this_grid();

    for (int s = 0; s < TD; ++s) {
        float* prC = (s & 1) ? pr1 : pr0;
        float* PsC = (s & 1) ? Ps1 : Ps0;
        const float* prP = (s & 1) ? pr0 : pr1;
        const float* PsP = (s & 1) ? Ps0 : Ps1;

        // query (independent loads — compiler hoists above phase1 waits)
        const float* qrow = dec + ((size_t)b * TD + s) * E_;
        float qb[4];
        #pragma unroll
        for (int ut = 0; ut < 4; ++ut) qb[ut] = qrow[uu[ut]] + bar[ut];

        // ---- phase 1: finish step s-1 softmax, update paW, write eout ----
        if (s > 0) {
            if (tid < NCH) red[tid] = PsP[b * NCH + tid];
            __syncthreads();
            float S = 0.0f;
            #pragma unroll
            for (int k = 0; k < NCH; ++k) S += red[k];
            float inv = 1.0f / S;
            if (tid < CHUNK + 2 * KH) {
                int t = t0 - KH + tid;
                float pv = (t >= 0 && t < TE) ? prP[(size_t)b * TE + t] : 0.0f;
                float pn = pv * inv;
                paW[tid] += pn;
                if (tid >= KH && tid < KH + CHUNK)
                    eout[((size_t)b * TD + (s - 1)) * TE + t] = pn;
            }
            __syncthreads();
        }

        // ---- phase 2: conv -> bf16 hi/lo A-frags [t][c] ----
        {
            const int c    = tid & 31;
            const int ts   = tid >> 5;        // 0..15, 8 t each
            const int base = ts * 8;
            float pw[K_ + 7];
            #pragma unroll
            for (int m = 0; m < K_ + 7; ++m) pw[m] = paW[base + m];
            float a[8];
            #pragma unroll
            for (int i = 0; i < 8; ++i) a[i] = cbS[c];
            #pragma unroll
            for (int k = 0; k < K_; ++k) {
                float wv = cwS[k * F_ + c];
                #pragma unroll
                for (int i = 0; i < 8; ++i) a[i] = fmaf(wv, pw[k + i], a[i]);
            }
            #pragma unroll
            for (int i = 0; i < 8; ++i) {
                unsigned short h = f2bf(a[i]);
                fThS[(base + i) * F_ + c] = h;
                fTlS[(base + i) * F_ + c] = f2bf(a[i] - bf2f(h));
            }
        }
        __syncthreads();

        // ---- phase 3: split-bf16 MFMA + tanh epilogue vs encR ----
        const short8* AH = (const short8*)fThS;
        const short8* AL = (const short8*)fTlS;
        #pragma unroll
        for (int tt = 0; tt < 8; ++tt) {
            short8 ah = AH[(tt * 16 + n16) * 4 + q];
            short8 al = AL[(tt * 16 + n16) * 4 + q];
            f32x4 acc[4];
            #pragma unroll
            for (int ut = 0; ut < 4; ++ut) {
                acc[ut] = (f32x4){0, 0, 0, 0};
                acc[ut] = __builtin_amdgcn_mfma_f32_16x16x32_bf16(ah, bh[ut], acc[ut], 0, 0, 0);
                acc[ut] = __builtin_amdgcn_mfma_f32_16x16x32_bf16(al, bh[ut], acc[ut], 0, 0, 0);
                acc[ut] = __builtin_amdgcn_mfma_f32_16x16x32_bf16(ah, bl[ut], acc[ut], 0, 0, 0);
            }
            #pragma unroll
            for (int r = 0; r < 4; ++r) {
                const int tl = tt * 16 + q * 4 + r;
                float sv = 0.0f;
                #pragma unroll
                for (int ut = 0; ut < 4; ++ut) {
                    float x  = acc[ut][r] + encR[tt][r][ut] + qb[ut];
                    float rr = __builtin_amdgcn_exp2f(x * KK);
                    float th = fmaf(-2.0f, __builtin_amdgcn_rcpf(rr + 1.0f), 1.0f);
                    sv = fmaf(vvr[ut], th, sv);
                }
                sv += __shfl_xor(sv, 1);
                sv += __shfl_xor(sv, 2);
                sv += __shfl_xor(sv, 4);
                sv += __shfl_xor(sv, 8);
                if (n16 == 0) redT[tl][w] = sv;
            }
        }
        __syncthreads();

        // ---- phase 4: e -> p=exp(e), write praw + chunk partial ----
        if (tid < CHUNK) {
            float e = 0.0f;
            #pragma unroll
            for (int k = 0; k < 8; ++k) e += redT[tid][k];
            // max-free: |e| <= sum|v_a| <= 25.6 -> exp2 arg <= 37, safe fp32
            float p = __builtin_amdgcn_exp2f(e * L2E);
            prC[(size_t)b * TE + t0 + tid] = p;
            float sp = p;
            #pragma unroll
            for (int off = 32; off; off >>= 1) sp += __shfl_xor(sp, off);
            if (g == 0) red[w] = sp;          // w = 0 or 1 (tid<128)
        }
        __syncthreads();
        if (tid == 0) PsC[b * NCH + chunk] = red[0] + red[1];

        __threadfence();
        grid.sync();
    }

    // ---- tail: softmax of last step (s = TD-1, buffers: pr1/Ps1) ----
    if (tid < NCH) red[tid] = Ps1[b * NCH + tid];
    __syncthreads();
    {
        float S = 0.0f;
        #pragma unroll
        for (int k = 0; k < NCH; ++k) S += red[k];
        float inv = 1.0f / S;
        if (tid < CHUNK) {
            int t = t0 + tid;
            eout[((size_t)b * TD + (TD - 1)) * TE + t] =
                pr1[(size_t)b * TE + t] * inv;
        }
    }
}

// ---------------------------------------------------------------------------
// Context matmul: c[b,d,e] = sum_t eo[b,d,t] * enc[b,t,e]
// ---------------------------------------------------------------------------
__global__ __launch_bounds__(256)
void context_kernel(const float* __restrict__ eo,   // B,TD,TE
                    const float* __restrict__ enc,  // B,TE,E
                    float* __restrict__ cout)       // B,TD,E
{
    __shared__ float eoT[64][36];
    const int b = blockIdx.y, d0 = blockIdx.x * 32, tid = threadIdx.x;

    float2 acc[32];
    #pragma unroll
    for (int d = 0; d < 32; ++d) { acc[d].x = 0.0f; acc[d].y = 0.0f; }

    for (int tc = 0; tc < TE / 64; ++tc) {
        __syncthreads();
        #pragma unroll
        for (int r = 0; r < 8; ++r) {
            int lin = r * 256 + tid;
            int d = lin >> 6, t = lin & 63;
            eoT[t][d] = eo[((size_t)b * TD + d0 + d) * TE + tc * 64 + t];
        }
        __syncthreads();
        #pragma unroll 4
        for (int t = 0; t < 64; ++t) {
            float2 ev = *(const float2*)&enc[((size_t)b * TE + tc * 64 + t) * E_ + 2 * tid];
            #pragma unroll
            for (int dq = 0; dq < 8; ++dq) {
                float4 wv = *(const float4*)&eoT[t][dq * 4];
                acc[dq * 4 + 0].x += wv.x * ev.x; acc[dq * 4 + 0].y += wv.x * ev.y;
                acc[dq * 4 + 1].x += wv.y * ev.x; acc[dq * 4 + 1].y += wv.y * ev.y;
                acc[dq * 4 + 2].x += wv.z * ev.x; acc[dq * 4 + 2].y += wv.z * ev.y;
                acc[dq * 4 + 3].x += wv.w * ev.x; acc[dq * 4 + 3].y += wv.w * ev.y;
            }
        }
    }
    #pragma unroll
    for (int d = 0; d < 32; ++d)
        *(float2*)&cout[((size_t)b * TD + d0 + d) * E_ + 2 * tid] = acc[d];
}

// ---------------------------------------------------------------------------
extern "C" void kernel_launch(void* const* d_in, const int* in_sizes, int n_in,
                              void* d_out, int out_size, void* d_ws, size_t ws_size,
                              hipStream_t stream) {
    const float* enc  = (const float*)d_in[0];
    const float* dec  = (const float*)d_in[1];
    const float* cw   = (const float*)d_in[2];
    const float* cb   = (const float*)d_in[3];
    const float* wloc = (const float*)d_in[4];
    const float* va   = (const float*)d_in[5];
    const float* ba   = (const float*)d_in[6];

    float* c_out = (float*)d_out;                          // B*TD*E
    float* e_out = (float*)d_out + (size_t)B_ * TD * E_;   // B*TD*TE

    float* ws  = (float*)d_ws;
    float* pr0 = ws;
    float* pr1 = pr0 + (size_t)B_ * TE;
    float* Ps0 = pr1 + (size_t)B_ * TE;
    float* Ps1 = Ps0 + 256;
    unsigned short* WTh = (unsigned short*)(Ps1 + 256);
    unsigned short* WTl = WTh + 512 * F_;

    prep_kernel<<<1, 512, 0, stream>>>(wloc, WTh, WTl);

    void* args[] = {(void*)&enc, (void*)&dec, (void*)&cw, (void*)&cb,
                    (void*)&WTh, (void*)&WTl, (void*)&va, (void*)&ba,
                    (void*)&pr0, (void*)&pr1, (void*)&Ps0, (void*)&Ps1,
                    (void*)&e_out};
    hipLaunchCooperativeKernel((void*)persist_kernel, dim3(NBLK), dim3(512),
                               args, 0, stream);

    context_kernel<<<dim3(TD / 32, B_), 256, 0, stream>>>(e_out, enc, c_out);
}